// Round 13
// baseline (279.344 us; speedup 1.0000x reference)
//
#include <hip/hip_runtime.h>
#include <math.h>

// ---------------------------------------------------------------------------
// EncoderGPECls: kNN(16) -> PCA curvature blend -> adaptive GPE embeddings
// xyz: [8,4096,3] f32  ->  out: [8,4096,128] f32
//
// R13 = R12 with the candidate stream moved OFF the LDS pipe.
//   R12 post-mortem: 2x waves (R11->R12) gave only -4% => dual-bound:
//   VALU issue ~80us AND LDS pipe ~82us (16384 ds_read_b128/CU, broadcast).
//   Candidates are wave-uniform -> load them via the SCALAR pipe instead:
//   prep_kernel repacks xyz to a float4 array in ws; knn reads candidates as
//   uniform loads (wv readfirstlane'd so divergence analysis scalarizes to
//   s_load_dwordx4; VMEM fallback still avoids LDS). LDS keeps only the
//   8.7KB survivor/merge arena. No pts preamble. Addressing moves to the
//   scalar unit. tau = exact md[16], no margin (single fmaf-fixed d2f makes
//   pass-2 survivors the exact top-17 set; tie overflow clamp = jax drop).
//   Divergent gathers (drains/merge/epilogue) = global VMEM, L2-hot.
//   Selection semantics: exact u64 (d2,idx) keys = jax lower-index tie-break.
//
// ws float layout:
//   [0, 32768)            curv per point
//   [32768, 131072)       rasig2 (3 SoA planes of 32768)
//   [131072, 131584)      curv partial sums [b][chunk] (8 x 64)
//   [131584, 131680)      per-batch raw sums as 48 DOUBLES
//   [131712, 262784)      pts4: float4 (x,y,z,0) per batch (8 x 4096)
// ---------------------------------------------------------------------------

#define NPTS 4096
#define KNN 17          // 16 neighbors + self (self contributes zero to sums)
#define BLKT 512        // 8 waves; 64 queries per block (1 per lane)
#define ESIZE 512       // candidates per wave (eighth)
#define SEG 256         // pass-2 segment size (u8 offsets)
#define SCAP 17         // survivor slots per lane per segment

#define WS_CURV  0
#define WS_RAS2  32768
#define WS_CSUM  131072
#define WS_STAT  131584
#define WS_PTS   131712

typedef unsigned long long ull;
#define SENT 0x7F800000FFFFFFFFULL   // (+inf bits, idx=max) sentinel key

// THE single d2 definition: explicit fmaf chain, identical IEEE ops at every
// call site (no contraction freedom). All passes/merges use this.
__device__ __forceinline__ float d2f(float qx, float qy, float qz,
                                     float cx, float cy, float cz) {
    float dx = qx - cx, dy = qy - cy, dz = qz - cz;
    return __builtin_fmaf(dz, dz, __builtin_fmaf(dy, dy, dx * dx));
}

// predicated replace-max insert of packed (d2bits<<32|idx) key; serial argmax
__device__ __forceinline__ void insertp(ull v, bool ins, ull (&md)[KNN],
                                        ull& maxv, int& maxp) {
#pragma unroll
    for (int k = 0; k < KNN; k++) {
        bool sel = ins && (k == maxp);
        md[k] = sel ? v : md[k];
    }
    maxv = md[0]; maxp = 0;
#pragma unroll
    for (int k = 1; k < KNN; k++) {
        bool g = md[k] > maxv;
        maxv = g ? md[k] : maxv;
        maxp = g ? k : maxp;
    }
}

// ---------------- prep: repack xyz -> float4 + per-batch double stats ------
__global__ __launch_bounds__(512) void prep_kernel(const float* __restrict__ xyz,
                                                   float* __restrict__ ws) {
    __shared__ double dst[48];
    int b = blockIdx.x;
    int tid = threadIdx.x;
    const float* base = xyz + b * NPTS * 3;
    float4* pts4 = (float4*)(ws + WS_PTS) + b * NPTS;

    double sx = 0, sy = 0, sz = 0, qxx = 0, qyy = 0, qzz = 0;
    for (int p = tid; p < NPTS; p += 512) {
        float x = base[p * 3], y = base[p * 3 + 1], z = base[p * 3 + 2];
        pts4[p] = make_float4(x, y, z, 0.0f);
        sx += (double)x; sy += (double)y; sz += (double)z;
        qxx += (double)x * x; qyy += (double)y * y; qzz += (double)z * z;
    }
    for (int off = 32; off > 0; off >>= 1) {
        sx += __shfl_down(sx, off);  sy += __shfl_down(sy, off);
        sz += __shfl_down(sz, off);  qxx += __shfl_down(qxx, off);
        qyy += __shfl_down(qyy, off); qzz += __shfl_down(qzz, off);
    }
    int wid = tid >> 6;
    if ((tid & 63) == 0) {
        dst[wid * 6 + 0] = sx;  dst[wid * 6 + 1] = sy;  dst[wid * 6 + 2] = sz;
        dst[wid * 6 + 3] = qxx; dst[wid * 6 + 4] = qyy; dst[wid * 6 + 5] = qzz;
    }
    __syncthreads();
    if (tid == 0) {
        double* wd = (double*)(ws + WS_STAT);
        for (int q = 0; q < 6; q++) {
            double a = 0.0;
            for (int w = 0; w < 8; w++) a += dst[w * 6 + q];
            wd[b * 6 + q] = a;
        }
    }
}

// ---------------- 3x3 symmetric eigensolve (double, trig method) -----------
__device__ __forceinline__ float curv_from_cov(float c00, float c01, float c02,
                                               float c11, float c12, float c22) {
    double a00 = c00, a01 = c01, a02 = c02, a11 = c11, a12 = c12, a22 = c22;
    double tr = a00 + a11 + a22;
    double q  = tr * (1.0 / 3.0);
    double b00 = a00 - q, b11 = a11 - q, b22 = a22 - q;
    double p2 = b00 * b00 + b11 * b11 + b22 * b22
              + 2.0 * (a01 * a01 + a02 * a02 + a12 * a12);
    double lmin;
    if (p2 < 1e-60) {
        lmin = q;
    } else {
        double p  = sqrt(p2 * (1.0 / 6.0));
        double ip = 1.0 / p;
        double m00 = b00 * ip, m11 = b11 * ip, m22 = b22 * ip;
        double m01 = a01 * ip, m02 = a02 * ip, m12 = a12 * ip;
        double det = m00 * (m11 * m22 - m12 * m12)
                   - m01 * (m01 * m22 - m12 * m02)
                   + m02 * (m01 * m12 - m11 * m02);
        double r = 0.5 * det;
        r = r > 1.0 ? 1.0 : (r < -1.0 ? -1.0 : r);
        double phi = acos(r) * (1.0 / 3.0);
        lmin = q + 2.0 * p * cos(phi + 2.0943951023931953);
    }
    return (float)(lmin / (tr + 1e-6));
}

// ---------------- kNN + covariance + curvature + lstd ----------------------
__global__ __launch_bounds__(BLKT, 4) void knn_kernel(float* __restrict__ ws) {
    __shared__ ull arena[1088];                  // 8704 B (sbuf | pub aliased)
    unsigned char* sbuf = (unsigned char*)arena; // [SCAP][BLKT] u8 survivors
    unsigned short* pub = (unsigned short*)arena;// 4 regions x 64x17 u16 idx
    int b = blockIdx.x >> 6;                     // 64 blocks per batch
    int chunk = blockIdx.x & 63;
    int tid = threadIdx.x;
    const float4* pts = (const float4*)(ws + WS_PTS) + b * NPTS;

    int wv = __builtin_amdgcn_readfirstlane(tid >> 6);  // uniform wave id
    int lane = tid & 63;
    int i = chunk * 64 + lane;                   // this lane's query (in-batch)
    float4 qp = pts[i];                          // divergent load (1x)
    int cbase = wv * ESIZE;                      // uniform candidate base

    // ---- pass 1: branch-free med3 sorted top-17 (values only) -------------
    float md[KNN];
#pragma unroll
    for (int k = 0; k < KNN; k++) md[k] = 3.4e38f;

    float4 cc[4];
#pragma unroll
    for (int u = 0; u < 4; u++) cc[u] = pts[cbase + u];   // uniform -> s_load
    for (int m = 0; m < ESIZE; m += 4) {
        float4 cu[4];
#pragma unroll
        for (int u = 0; u < 4; u++) cu[u] = cc[u];
        int mn = (m + 4 < ESIZE) ? (m + 4) : 0;  // last prefetch redundant
#pragma unroll
        for (int u = 0; u < 4; u++) cc[u] = pts[cbase + mn + u];
#pragma unroll
        for (int u = 0; u < 4; u++) {
            float d2 = d2f(qp.x, qp.y, qp.z, cu[u].x, cu[u].y, cu[u].z);
#pragma unroll
            for (int k = KNN - 1; k >= 1; k--)   // descending: reads olds only
                md[k] = __builtin_amdgcn_fmed3f(d2, md[k - 1], md[k]);
            md[0] = fminf(d2, md[0]);
        }
    }
    float tau = md[KNN - 1];                     // EXACT 17th (d2f everywhere)

    // ---- pass 2 (2 segments of 256): u8 survivor offsets + exact select ---
    ull k17[KNN];
#pragma unroll
    for (int k = 0; k < KNN; k++) k17[k] = SENT;
    ull maxv = SENT; int maxp = 0;

#pragma unroll
    for (int sgi = 0; sgi < 2; sgi++) {
        int segbase = cbase + sgi * SEG;
        int cnt = 0;
#pragma unroll
        for (int u = 0; u < 4; u++) cc[u] = pts[segbase + u];
        for (int m = 0; m < SEG; m += 4) {
            float4 cu[4];
#pragma unroll
            for (int u = 0; u < 4; u++) cu[u] = cc[u];
            int mn = (m + 4 < SEG) ? (m + 4) : 0;
#pragma unroll
            for (int u = 0; u < 4; u++) cc[u] = pts[segbase + mn + u];
#pragma unroll
            for (int u = 0; u < 4; u++) {
                float d2 = d2f(qp.x, qp.y, qp.z, cu[u].x, cu[u].y, cu[u].z);
                if (d2 <= tau) {                 // exact top-17 set (+ exact ties)
                    if (cnt < SCAP) sbuf[cnt * BLKT + tid] = (unsigned char)(m + u);
                    cnt++;                       // overflow clamp = jax tie drop
                }
            }
        }
        if (cnt > SCAP) cnt = SCAP;
        // drain this segment's survivors into the exact u64 top-17
#pragma unroll
        for (int t = 0; t < SCAP; t++) {
            if (__any(t < cnt)) {
                int ix = segbase + sbuf[t * BLKT + tid];
                float4 c = pts[ix];              // divergent gather, L2-hot
                float d2 = d2f(qp.x, qp.y, qp.z, c.x, c.y, c.z);
                ull key = ((ull)__float_as_uint(d2) << 32) | (unsigned)ix;
                bool ins = (t < cnt) && (key < maxv);
                if (__any(ins)) insertp(key, ins, k17, maxv, maxp);
            }
        }
    }

    // ---- 3-round tournament merge (u16 idx publish, keys rebuilt exactly) --
    __syncthreads();                             // sbuf dead -> pub reuse safe
    if (wv & 1) {
#pragma unroll
        for (int k = 0; k < KNN; k++)
            pub[(wv >> 1) * 1088 + lane * KNN + k] = (unsigned short)(k17[k] & 0xffffULL);
    }
    __syncthreads();
    if (!(wv & 1)) {
        int r = wv >> 1;
#pragma unroll
        for (int k = 0; k < KNN; k++) {
            int ix = pub[r * 1088 + lane * KNN + k];
            float4 c = pts[ix];
            float d2 = d2f(qp.x, qp.y, qp.z, c.x, c.y, c.z);
            ull key = ((ull)__float_as_uint(d2) << 32) | (unsigned)ix;
            bool ins = key < maxv;
            if (__any(ins)) insertp(key, ins, k17, maxv, maxp);
        }
    }
    __syncthreads();
    if (wv == 2 || wv == 6) {
#pragma unroll
        for (int k = 0; k < KNN; k++)
            pub[(wv >> 2) * 1088 + lane * KNN + k] = (unsigned short)(k17[k] & 0xffffULL);
    }
    __syncthreads();
    if (wv == 0 || wv == 4) {
        int r = wv >> 2;
#pragma unroll
        for (int k = 0; k < KNN; k++) {
            int ix = pub[r * 1088 + lane * KNN + k];
            float4 c = pts[ix];
            float d2 = d2f(qp.x, qp.y, qp.z, c.x, c.y, c.z);
            ull key = ((ull)__float_as_uint(d2) << 32) | (unsigned)ix;
            bool ins = key < maxv;
            if (__any(ins)) insertp(key, ins, k17, maxv, maxp);
        }
    }
    __syncthreads();
    if (wv == 4) {
#pragma unroll
        for (int k = 0; k < KNN; k++)
            pub[lane * KNN + k] = (unsigned short)(k17[k] & 0xffffULL);
    }
    __syncthreads();

    // ---- epilogue on wave 0: final merge + moments -> curv, rasig2 --------
    if (wv == 0) {
#pragma unroll
        for (int k = 0; k < KNN; k++) {
            int ix = pub[lane * KNN + k];
            float4 c = pts[ix];
            float d2 = d2f(qp.x, qp.y, qp.z, c.x, c.y, c.z);
            ull key = ((ull)__float_as_uint(d2) << 32) | (unsigned)ix;
            bool ins = key < maxv;
            if (__any(ins)) insertp(key, ins, k17, maxv, maxp);
        }

        float s1x = 0, s1y = 0, s1z = 0;
        float cxx = 0, cxy = 0, cxz = 0, cyy = 0, cyz = 0, czz = 0;
#pragma unroll
        for (int k = 0; k < KNN; k++) {
            int j = (int)(k17[k] & 0xffffffffULL);
            float4 c = pts[j];
            float ux = c.x - qp.x, uy = c.y - qp.y, uz = c.z - qp.z;
            s1x += ux; s1y += uy; s1z += uz;
            cxx += ux * ux; cxy += ux * uy; cxz += ux * uz;
            cyy += uy * uy; cyz += uy * uz; czz += uz * uz;
        }
        const float i16 = 1.0f / 16.0f, i15 = 1.0f / 15.0f;
        float mx = s1x * i16, my = s1y * i16, mz = s1z * i16;
        float c00 = (cxx - 16.0f * mx * mx) * i15;
        float c01 = (cxy - 16.0f * mx * my) * i15;
        float c02 = (cxz - 16.0f * mx * mz) * i15;
        float c11 = (cyy - 16.0f * my * my) * i15;
        float c12 = (cyz - 16.0f * my * mz) * i15;
        float c22 = (czz - 16.0f * mz * mz) * i15;

        float curv = curv_from_cov(c00, c01, c02, c11, c12, c22);

        float v0 = c00 > 0.0f ? c00 : 0.0f;
        float v1 = c11 > 0.0f ? c11 : 0.0f;
        float v2 = c22 > 0.0f ? c22 : 0.0f;
        float r2x = 1.0f / (0.3f * (1.0f + sqrtf(v0)) + 1e-6f);
        float r2y = 1.0f / (0.3f * (1.0f + sqrtf(v1)) + 1e-6f);
        float r2z = 1.0f / (0.3f * (1.0f + sqrtf(v2)) + 1e-6f);

        int g = b * NPTS + i;
        ws[WS_CURV + g] = curv;
        ws[WS_RAS2 + 0 * 32768 + g] = r2x;
        ws[WS_RAS2 + 1 * 32768 + g] = r2y;
        ws[WS_RAS2 + 2 * 32768 + g] = r2z;

        // non-atomic per-(b,chunk) partial sum (no memset dispatch needed)
        float cs = curv;
        for (int off = 32; off > 0; off >>= 1) cs += __shfl_down(cs, off);
        if (lane == 0) ws[WS_CSUM + b * 64 + chunk] = cs;
    }
}

// ---------------- final embedding (scalars + cmeans per-block, parallel) ---
__global__ void out_kernel(const float* __restrict__ xyz,
                           const float* __restrict__ ws,
                           float* __restrict__ out) {
    __shared__ float sc[3];                      // rasig1, blend, 1-blend
    __shared__ float scm[8];                     // per-batch curv mean
    if (threadIdx.x < 64) {
        float part = 0.0f;
        if (threadIdx.x < 24) {
            const double* st = (const double*)(ws + WS_STAT);
            int bb = threadIdx.x / 3, dd = threadIdx.x % 3;
            double s = st[bb * 6 + dd], ss = st[bb * 6 + 3 + dd];
            double var = (ss - s * s / 4096.0) / 4095.0;
            part = (float)sqrt(var > 0.0 ? var : 0.0);
        }
        float p2 = part;
        for (int off = 32; off > 0; off >>= 1) p2 += __shfl_down(p2, off);
        if (threadIdx.x == 0) {
            float gf = p2 * (1.0f / 24.0f);
            float denom = 0.3f * (1.0f + gf) + 1e-6f;
            float blend = 1.0f / (1.0f + __expf(-(gf - 0.1f) * 10.0f));
            sc[0] = 1.0f / denom;
            sc[1] = blend;
            sc[2] = 1.0f - blend;
        }
        float cp = 0.0f;
        const float* pf = ws + WS_CSUM;
#pragma unroll
        for (int t = 0; t < 8; t++) cp += pf[threadIdx.x * 8 + t];
        cp += __shfl_down(cp, 4);
        cp += __shfl_down(cp, 2);
        cp += __shfl_down(cp, 1);
        if ((threadIdx.x & 7) == 0) scm[threadIdx.x >> 3] = cp * (1.0f / 4096.0f);
    }
    __syncthreads();

    int idx = blockIdx.x * 256 + (int)threadIdx.x;
    int j = idx & 127;
    int g = idx >> 7;
    int b = g >> 12;
    int f = (j < 127) ? j : 128;                      // OUT_IDX
    int d = (f >= 86) ? 2 : ((f >= 43) ? 1 : 0);
    int t = f - d * 43;
    float fv = (float)((double)(t + 1) * (2.0 / 44.0) - 1.0);  // FEAT_VAL[t]

    float x = xyz[g * 3 + d];
    float rasig1 = sc[0];
    float blend  = sc[1];
    float blendc = sc[2];
    float cmean  = scm[b];
    float curv   = ws[WS_CURV + g];
    float w = 1.0f / (1.0f + __expf(-10.0f * (curv - cmean)));

    float t1 = (x - fv) * rasig1;
    float e1 = blend * __expf(-0.5f * t1 * t1) + blendc * __cosf(t1);
    float t2 = (x - fv) * ws[WS_RAS2 + (d << 15) + g];
    float e2 = __expf(-0.5f * t2 * t2);
    out[idx] = w * e1 + (1.0f - w) * e2;
}

extern "C" void kernel_launch(void* const* d_in, const int* in_sizes, int n_in,
                              void* d_out, int out_size, void* d_ws, size_t ws_size,
                              hipStream_t stream) {
    const float* xyz = (const float*)d_in[0];
    float* out = (float*)d_out;
    float* ws = (float*)d_ws;

    prep_kernel<<<8, 512, 0, stream>>>(xyz, ws);
    knn_kernel<<<512, BLKT, 0, stream>>>(ws);
    out_kernel<<<out_size / 256, 256, 0, stream>>>(xyz, ws, out);
}

// Round 14
// 273.837 us; speedup vs baseline: 1.0201x; 1.0201x over previous
//
#include <hip/hip_runtime.h>
#include <math.h>

// ---------------------------------------------------------------------------
// EncoderGPECls: kNN(16) -> PCA curvature blend -> adaptive GPE embeddings
// xyz: [8,4096,3] f32  ->  out: [8,4096,128] f32
//
// R14: bucket-sorted windowed kNN with per-wave independent termination.
//   R13 post-mortem: LDS vs scalar candidate paths and 2 vs 4 waves/SIMD all
//   land ~215-220us -> ~60% stall is structural; the remaining proportional
//   lever is CANDIDATE COUNT. R6/R9's windowed attempts failed on occupancy
//   and gated-insert subset bloat -- both fixed here: R12's 8-wave shell
//   (4 waves/SIMD) + med3 selection (unconditional cost; loose subset-tau
//   only widens the window, never the per-candidate cost).
//   sort_kernel: counting sort by x (256 analytic buckets, 3 barriers vs
//     bitonic's 78 which made R6's presort ~88us) -> sorted (x,y,z,orig) in
//     ws + per-64-chunk suffix-min/prefix-max of x (exact bounds despite
//     intra-bucket disorder) + double stats.
//   knn: block = 64 rank-consecutive queries, 8 waves; wave w owns chunk
//     8s+w of each 512-rank slab. Scan home slab; extend each side
//     independently (no barriers): side closes on
//     __all(max(0,sufmin[next]-xq)^2 >= md[16]).
//     Exactness: any point never scanned by its owner wave fails that
//     owner's bound => d2 >= tau_w >= tau_global => not a true neighbor.
//   Pass 2 replays the recorded slab range (same fmaf-fixed d2f), survivors
//   (d2<=tau, exactly 17+ties) -> u16-rank slots -> exact u64 (d2,rank)
//   select; R13 3-round u16 tournament merge; wave-0 epilogue.
//
// ws float layout:
//   [0, 32768)            curv per point
//   [32768, 131072)       rasig2 (3 SoA planes of 32768)
//   [131072, 131584)      curv partial sums [b][chunk] (8 x 64)
//   [131584, 131680)      per-batch raw sums as 48 DOUBLES
//   [131712, 262784)      sorted float4 (x,y,z,origidx) per batch
//   [262784, 263296)      sufmin  [b][chunk]  (8 x 64)
//   [263296, 263808)      prefmax [b][chunk]  (8 x 64)
// ---------------------------------------------------------------------------

#define NPTS 4096
#define KNN 17          // 16 neighbors + self (self contributes zero to sums)
#define SCAP 20         // survivor u16 slots per lane
#define BLKT 512        // 8 waves; 64 queries per block (1 per lane)
#define NBUCK 256

#define WS_CURV    0
#define WS_RAS2    32768
#define WS_CSUM    131072
#define WS_STAT    131584
#define WS_SORT    131712
#define WS_SUFMIN  262784
#define WS_PREFMAX 263296

typedef unsigned long long ull;
#define SENT 0x7F800000FFFFFFFFULL   // (+inf bits, idx=max) sentinel key

// THE single d2 definition: explicit fmaf chain, identical IEEE ops at every
// call site (no contraction freedom) -> pass-2 replay is bit-identical.
__device__ __forceinline__ float d2f(float qx, float qy, float qz,
                                     float cx, float cy, float cz) {
    float dx = qx - cx, dy = qy - cy, dz = qz - cz;
    return __builtin_fmaf(dz, dz, __builtin_fmaf(dy, dy, dx * dx));
}

// predicated replace-max insert of packed (d2bits<<32|rank) key; serial argmax
__device__ __forceinline__ void insertp(ull v, bool ins, ull (&md)[KNN],
                                        ull& maxv, int& maxp) {
#pragma unroll
    for (int k = 0; k < KNN; k++) {
        bool sel = ins && (k == maxp);
        md[k] = sel ? v : md[k];
    }
    maxv = md[0]; maxp = 0;
#pragma unroll
    for (int k = 1; k < KNN; k++) {
        bool g = md[k] > maxv;
        maxv = g ? md[k] : maxv;
        maxp = g ? k : maxp;
    }
}

// ---------------- counting sort by x + chunk bounds + double stats ---------
__global__ __launch_bounds__(1024) void sort_kernel(const float* __restrict__ xyz,
                                                    float* __restrict__ ws) {
    __shared__ int hist[NBUCK];
    __shared__ int boff[NBUCK];
    __shared__ float xs[NPTS];                   // 16 KB sorted x copy
    __shared__ double dst[96];
    __shared__ float cmin[64], cmax[64];
    int b = blockIdx.x, tid = threadIdx.x;
    const float* base = xyz + b * NPTS * 3;
    if (tid < NBUCK) hist[tid] = 0;
    __syncthreads();

    double sx = 0, sy = 0, sz = 0, qxx = 0, qyy = 0, qzz = 0;
    for (int p = tid; p < NPTS; p += 1024) {
        float x = base[p * 3], y = base[p * 3 + 1], z = base[p * 3 + 2];
        sx += (double)x; sy += (double)y; sz += (double)z;
        qxx += (double)x * x; qyy += (double)y * y; qzz += (double)z * z;
        int bk = (int)((x + 5.0f) * 25.6f);      // 256 buckets over [-5,5]
        bk = bk < 0 ? 0 : (bk > 255 ? 255 : bk); // clamp: bounds stay exact
        atomicAdd(&hist[bk], 1);
    }
    for (int off = 32; off > 0; off >>= 1) {
        sx += __shfl_down(sx, off);  sy += __shfl_down(sy, off);
        sz += __shfl_down(sz, off);  qxx += __shfl_down(qxx, off);
        qyy += __shfl_down(qyy, off); qzz += __shfl_down(qzz, off);
    }
    int wid = tid >> 6;
    if ((tid & 63) == 0) {
        dst[wid * 6 + 0] = sx;  dst[wid * 6 + 1] = sy;  dst[wid * 6 + 2] = sz;
        dst[wid * 6 + 3] = qxx; dst[wid * 6 + 4] = qyy; dst[wid * 6 + 5] = qzz;
    }
    __syncthreads();
    if (tid == 0) {                              // exclusive scan (serial, 256)
        int a = 0;
        for (int k = 0; k < NBUCK; k++) { boff[k] = a; a += hist[k]; }
    }
    __syncthreads();

    float4* out4 = (float4*)(ws + WS_SORT) + b * NPTS;
    for (int p = tid; p < NPTS; p += 1024) {
        float x = base[p * 3], y = base[p * 3 + 1], z = base[p * 3 + 2];
        int bk = (int)((x + 5.0f) * 25.6f);
        bk = bk < 0 ? 0 : (bk > 255 ? 255 : bk);
        int pos = atomicAdd(&boff[bk], 1);
        out4[pos] = make_float4(x, y, z, __int_as_float(p));
        xs[pos] = x;
    }
    __syncthreads();
    if (tid < 64) {                              // per-chunk x min/max
        float mn = 3.4e38f, mx = -3.4e38f;
        for (int t = 0; t < 64; t++) {
            float v = xs[tid * 64 + t];
            mn = fminf(mn, v); mx = fmaxf(mx, v);
        }
        cmin[tid] = mn; cmax[tid] = mx;
    }
    __syncthreads();
    if (tid == 0) {
        float m = 3.4e38f;
        for (int c = 63; c >= 0; c--) { m = fminf(m, cmin[c]); ws[WS_SUFMIN + b * 64 + c] = m; }
        float M = -3.4e38f;
        for (int c = 0; c < 64; c++) { M = fmaxf(M, cmax[c]); ws[WS_PREFMAX + b * 64 + c] = M; }
        double* wd = (double*)(ws + WS_STAT);
        for (int q = 0; q < 6; q++) {
            double a = 0.0;
            for (int w = 0; w < 16; w++) a += dst[w * 6 + q];
            wd[b * 6 + q] = a;
        }
    }
}

// ---------------- 3x3 symmetric eigensolve (double, trig method) -----------
__device__ __forceinline__ float curv_from_cov(float c00, float c01, float c02,
                                               float c11, float c12, float c22) {
    double a00 = c00, a01 = c01, a02 = c02, a11 = c11, a12 = c12, a22 = c22;
    double tr = a00 + a11 + a22;
    double q  = tr * (1.0 / 3.0);
    double b00 = a00 - q, b11 = a11 - q, b22 = a22 - q;
    double p2 = b00 * b00 + b11 * b11 + b22 * b22
              + 2.0 * (a01 * a01 + a02 * a02 + a12 * a12);
    double lmin;
    if (p2 < 1e-60) {
        lmin = q;
    } else {
        double p  = sqrt(p2 * (1.0 / 6.0));
        double ip = 1.0 / p;
        double m00 = b00 * ip, m11 = b11 * ip, m22 = b22 * ip;
        double m01 = a01 * ip, m02 = a02 * ip, m12 = a12 * ip;
        double det = m00 * (m11 * m22 - m12 * m12)
                   - m01 * (m01 * m22 - m12 * m02)
                   + m02 * (m01 * m12 - m11 * m02);
        double r = 0.5 * det;
        r = r > 1.0 ? 1.0 : (r < -1.0 ? -1.0 : r);
        double phi = acos(r) * (1.0 / 3.0);
        lmin = q + 2.0 * p * cos(phi + 2.0943951023931953);
    }
    return (float)(lmin / (tr + 1e-6));
}

// ---------------- kNN + covariance + curvature + lstd ----------------------
__global__ __launch_bounds__(BLKT, 4) void knn_kernel(float* __restrict__ ws) {
    __shared__ unsigned short sbuf[SCAP * BLKT]; // 20 KB survivors / pub alias
    __shared__ float sufmin_s[64], prefmax_s[64];
    unsigned short* pub = sbuf;                  // 4 regions x 64x17 u16 ranks
    int b = blockIdx.x >> 6;                     // 64 blocks per batch
    int q = blockIdx.x & 63;                     // query chunk (sorted ranks)
    int tid = threadIdx.x;
    const float4* pts = (const float4*)(ws + WS_SORT) + b * NPTS;
    if (tid < 64) {
        sufmin_s[tid]  = ws[WS_SUFMIN + b * 64 + tid];
        prefmax_s[tid] = ws[WS_PREFMAX + b * 64 + tid];
    }
    __syncthreads();

    int wv = tid >> 6, lane = tid & 63;
    int qrank = q * 64 + lane;
    float4 qp = pts[qrank];                      // coalesced gather
    float xq = qp.x;
    int s0 = q >> 3;                             // home slab (8 slabs of 512)

    // ---- pass 1: med3 top-17 values over owned chunks, adaptive window ----
    float md[KNN];
#pragma unroll
    for (int k = 0; k < KNN; k++) md[k] = 3.4e38f;

    auto scan1 = [&](int cb) {                   // cb = chunk base rank
        float4 cc[4];
#pragma unroll
        for (int u = 0; u < 4; u++) cc[u] = pts[cb + u];
        for (int m = 0; m < 64; m += 4) {
            float4 cu[4];
#pragma unroll
            for (int u = 0; u < 4; u++) cu[u] = cc[u];
            int mn = (m + 4 < 64) ? (m + 4) : 0;
#pragma unroll
            for (int u = 0; u < 4; u++) cc[u] = pts[cb + mn + u];
#pragma unroll
            for (int u = 0; u < 4; u++) {
                float d2 = d2f(qp.x, qp.y, qp.z, cu[u].x, cu[u].y, cu[u].z);
#pragma unroll
                for (int k = KNN - 1; k >= 1; k--)
                    md[k] = __builtin_amdgcn_fmed3f(d2, md[k - 1], md[k]);
                md[0] = fminf(d2, md[0]);
            }
        }
    };

    scan1((8 * s0 + wv) * 64);                   // home slab's owned chunk
    int sL = s0, sR = s0;
    bool openR = (sR < 7), openL = (sL > 0);
    while (openR || openL) {
        if (openR) {
            float e = sufmin_s[8 * (sR + 1) + wv];
            float gap = fmaxf(e - xq, 0.0f);
            if (__all(gap * gap >= md[KNN - 1])) openR = false;  // exact bound
            else { scan1((8 * (sR + 1) + wv) * 64); sR++; openR = (sR < 7); }
        }
        if (openL) {
            float e = prefmax_s[8 * (sL - 1) + wv];
            float gap = fmaxf(xq - e, 0.0f);
            if (__all(gap * gap >= md[KNN - 1])) openL = false;
            else { scan1((8 * (sL - 1) + wv) * 64); sL--; openL = (sL > 0); }
        }
    }
    float tau = md[KNN - 1];                     // exact 17th of wave subset

    // ---- pass 2: replay [sL..sR], survivors (d2<=tau) -> u16 rank slots ---
    int cnt = 0;
    for (int s = sL; s <= sR; s++) {
        int cb = (8 * s + wv) * 64;
        float4 cc[4];
#pragma unroll
        for (int u = 0; u < 4; u++) cc[u] = pts[cb + u];
        for (int m = 0; m < 64; m += 4) {
            float4 cu[4];
#pragma unroll
            for (int u = 0; u < 4; u++) cu[u] = cc[u];
            int mn = (m + 4 < 64) ? (m + 4) : 0;
#pragma unroll
            for (int u = 0; u < 4; u++) cc[u] = pts[cb + mn + u];
#pragma unroll
            for (int u = 0; u < 4; u++) {
                float d2 = d2f(qp.x, qp.y, qp.z, cu[u].x, cu[u].y, cu[u].z);
                if (d2 <= tau) {                 // exactly 17 + exact ties
                    if (cnt < SCAP) sbuf[cnt * BLKT + tid] = (unsigned short)(cb + m + u);
                    cnt++;
                }
            }
        }
    }
    if (cnt > SCAP) cnt = SCAP;                  // 4+ exact ties only

    // ---- exact u64 select over survivors ----------------------------------
    ull k17[KNN];
#pragma unroll
    for (int k = 0; k < KNN; k++) k17[k] = SENT;
    ull maxv = SENT; int maxp = 0;
#pragma unroll
    for (int t = 0; t < SCAP; t++) {
        if (__any(t < cnt)) {
            int ix = sbuf[t * BLKT + tid];
            float4 c = pts[ix];
            float d2 = d2f(qp.x, qp.y, qp.z, c.x, c.y, c.z);
            ull key = ((ull)__float_as_uint(d2) << 32) | (unsigned)ix;
            bool ins = (t < cnt) && (key < maxv);
            if (__any(ins)) insertp(key, ins, k17, maxv, maxp);
        }
    }

    // ---- 3-round tournament merge (u16 rank publish, keys rebuilt) --------
    __syncthreads();                             // sbuf dead -> pub reuse safe
    if (wv & 1) {
#pragma unroll
        for (int k = 0; k < KNN; k++)
            pub[(wv >> 1) * 1088 + lane * KNN + k] = (unsigned short)(k17[k] & 0xffffULL);
    }
    __syncthreads();
    if (!(wv & 1)) {
        int r = wv >> 1;
#pragma unroll
        for (int k = 0; k < KNN; k++) {
            int ix = pub[r * 1088 + lane * KNN + k];
            float4 c = pts[ix];
            float d2 = d2f(qp.x, qp.y, qp.z, c.x, c.y, c.z);
            ull key = ((ull)__float_as_uint(d2) << 32) | (unsigned)ix;
            bool ins = key < maxv;
            if (__any(ins)) insertp(key, ins, k17, maxv, maxp);
        }
    }
    __syncthreads();
    if (wv == 2 || wv == 6) {
#pragma unroll
        for (int k = 0; k < KNN; k++)
            pub[(wv >> 2) * 1088 + lane * KNN + k] = (unsigned short)(k17[k] & 0xffffULL);
    }
    __syncthreads();
    if (wv == 0 || wv == 4) {
        int r = wv >> 2;
#pragma unroll
        for (int k = 0; k < KNN; k++) {
            int ix = pub[r * 1088 + lane * KNN + k];
            float4 c = pts[ix];
            float d2 = d2f(qp.x, qp.y, qp.z, c.x, c.y, c.z);
            ull key = ((ull)__float_as_uint(d2) << 32) | (unsigned)ix;
            bool ins = key < maxv;
            if (__any(ins)) insertp(key, ins, k17, maxv, maxp);
        }
    }
    __syncthreads();
    if (wv == 4) {
#pragma unroll
        for (int k = 0; k < KNN; k++)
            pub[lane * KNN + k] = (unsigned short)(k17[k] & 0xffffULL);
    }
    __syncthreads();

    // ---- epilogue on wave 0: final merge + moments -> curv, rasig2 --------
    if (wv == 0) {
#pragma unroll
        for (int k = 0; k < KNN; k++) {
            int ix = pub[lane * KNN + k];
            float4 c = pts[ix];
            float d2 = d2f(qp.x, qp.y, qp.z, c.x, c.y, c.z);
            ull key = ((ull)__float_as_uint(d2) << 32) | (unsigned)ix;
            bool ins = key < maxv;
            if (__any(ins)) insertp(key, ins, k17, maxv, maxp);
        }

        float s1x = 0, s1y = 0, s1z = 0;
        float cxx = 0, cxy = 0, cxz = 0, cyy = 0, cyz = 0, czz = 0;
#pragma unroll
        for (int k = 0; k < KNN; k++) {
            int j = (int)(k17[k] & 0xffffULL);
            float4 c = pts[j];
            float ux = c.x - qp.x, uy = c.y - qp.y, uz = c.z - qp.z;
            s1x += ux; s1y += uy; s1z += uz;
            cxx += ux * ux; cxy += ux * uy; cxz += ux * uz;
            cyy += uy * uy; cyz += uy * uz; czz += uz * uz;
        }
        const float i16 = 1.0f / 16.0f, i15 = 1.0f / 15.0f;
        float mx = s1x * i16, my = s1y * i16, mz = s1z * i16;
        float c00 = (cxx - 16.0f * mx * mx) * i15;
        float c01 = (cxy - 16.0f * mx * my) * i15;
        float c02 = (cxz - 16.0f * mx * mz) * i15;
        float c11 = (cyy - 16.0f * my * my) * i15;
        float c12 = (cyz - 16.0f * my * mz) * i15;
        float c22 = (czz - 16.0f * mz * mz) * i15;

        float curv = curv_from_cov(c00, c01, c02, c11, c12, c22);

        float v0 = c00 > 0.0f ? c00 : 0.0f;
        float v1 = c11 > 0.0f ? c11 : 0.0f;
        float v2 = c22 > 0.0f ? c22 : 0.0f;
        float r2x = 1.0f / (0.3f * (1.0f + sqrtf(v0)) + 1e-6f);
        float r2y = 1.0f / (0.3f * (1.0f + sqrtf(v1)) + 1e-6f);
        float r2z = 1.0f / (0.3f * (1.0f + sqrtf(v2)) + 1e-6f);

        int g = b * NPTS + __float_as_int(qp.w); // original point index
        ws[WS_CURV + g] = curv;
        ws[WS_RAS2 + 0 * 32768 + g] = r2x;
        ws[WS_RAS2 + 1 * 32768 + g] = r2y;
        ws[WS_RAS2 + 2 * 32768 + g] = r2z;

        float cs = curv;
        for (int off = 32; off > 0; off >>= 1) cs += __shfl_down(cs, off);
        if (lane == 0) ws[WS_CSUM + b * 64 + q] = cs;   // non-atomic partial
    }
}

// ---------------- final embedding (scalars + cmeans per-block, parallel) ---
__global__ void out_kernel(const float* __restrict__ xyz,
                           const float* __restrict__ ws,
                           float* __restrict__ out) {
    __shared__ float sc[3];                      // rasig1, blend, 1-blend
    __shared__ float scm[8];                     // per-batch curv mean
    if (threadIdx.x < 64) {
        float part = 0.0f;
        if (threadIdx.x < 24) {
            const double* st = (const double*)(ws + WS_STAT);
            int bb = threadIdx.x / 3, dd = threadIdx.x % 3;
            double s = st[bb * 6 + dd], ss = st[bb * 6 + 3 + dd];
            double var = (ss - s * s / 4096.0) / 4095.0;
            part = (float)sqrt(var > 0.0 ? var : 0.0);
        }
        float p2 = part;
        for (int off = 32; off > 0; off >>= 1) p2 += __shfl_down(p2, off);
        if (threadIdx.x == 0) {
            float gf = p2 * (1.0f / 24.0f);
            float denom = 0.3f * (1.0f + gf) + 1e-6f;
            float blend = 1.0f / (1.0f + __expf(-(gf - 0.1f) * 10.0f));
            sc[0] = 1.0f / denom;
            sc[1] = blend;
            sc[2] = 1.0f - blend;
        }
        float cp = 0.0f;
        const float* pf = ws + WS_CSUM;
#pragma unroll
        for (int t = 0; t < 8; t++) cp += pf[threadIdx.x * 8 + t];
        cp += __shfl_down(cp, 4);
        cp += __shfl_down(cp, 2);
        cp += __shfl_down(cp, 1);
        if ((threadIdx.x & 7) == 0) scm[threadIdx.x >> 3] = cp * (1.0f / 4096.0f);
    }
    __syncthreads();

    int idx = blockIdx.x * 256 + (int)threadIdx.x;
    int j = idx & 127;
    int g = idx >> 7;
    int b = g >> 12;
    int f = (j < 127) ? j : 128;                      // OUT_IDX
    int d = (f >= 86) ? 2 : ((f >= 43) ? 1 : 0);
    int t = f - d * 43;
    float fv = (float)((double)(t + 1) * (2.0 / 44.0) - 1.0);  // FEAT_VAL[t]

    float x = xyz[g * 3 + d];
    float rasig1 = sc[0];
    float blend  = sc[1];
    float blendc = sc[2];
    float cmean  = scm[b];
    float curv   = ws[WS_CURV + g];
    float w = 1.0f / (1.0f + __expf(-10.0f * (curv - cmean)));

    float t1 = (x - fv) * rasig1;
    float e1 = blend * __expf(-0.5f * t1 * t1) + blendc * __cosf(t1);
    float t2 = (x - fv) * ws[WS_RAS2 + (d << 15) + g];
    float e2 = __expf(-0.5f * t2 * t2);
    out[idx] = w * e1 + (1.0f - w) * e2;
}

extern "C" void kernel_launch(void* const* d_in, const int* in_sizes, int n_in,
                              void* d_out, int out_size, void* d_ws, size_t ws_size,
                              hipStream_t stream) {
    const float* xyz = (const float*)d_in[0];
    float* out = (float*)d_out;
    float* ws = (float*)d_ws;

    sort_kernel<<<8, 1024, 0, stream>>>(xyz, ws);
    knn_kernel<<<512, BLKT, 0, stream>>>(ws);
    out_kernel<<<out_size / 256, 256, 0, stream>>>(xyz, ws, out);
}